// Round 11
// baseline (244.855 us; speedup 1.0000x reference)
//
#include <hip/hip_runtime.h>

#define D_MODEL 1024
#define T_SEQ   1024
#define BATCH   8
#define NHEAD   16
#define HDIM    64

typedef float      v4f   __attribute__((ext_vector_type(4)));
typedef _Float16   half8 __attribute__((ext_vector_type(8)));
typedef _Float16   half4h __attribute__((ext_vector_type(4)));
typedef unsigned int ui4 __attribute__((ext_vector_type(4)));

// async global->LDS, 16B per lane, dest = wave-uniform base + lane*16
__device__ __forceinline__ void load_lds16(const _Float16* g, _Float16* l) {
  __builtin_amdgcn_global_load_lds(
      (const __attribute__((address_space(1))) unsigned int*)g,
      (__attribute__((address_space(3))) unsigned int*)l, 16, 0, 0);
}

// ---------------- LayerNorm (fp32 in) -> fp16 xn ----------------
__global__ __launch_bounds__(256) void ln_kernel(const float* __restrict__ x,
                                                 const float* __restrict__ gamma,
                                                 const float* __restrict__ beta,
                                                 _Float16* __restrict__ xn) {
  int row = blockIdx.x;
  int tid = threadIdx.x;
  const float* xr = x + (size_t)row * D_MODEL;
  v4f xv = *(const v4f*)(xr + tid * 4);
  float s  = xv[0] + xv[1] + xv[2] + xv[3];
  float sq = xv[0]*xv[0] + xv[1]*xv[1] + xv[2]*xv[2] + xv[3]*xv[3];
#pragma unroll
  for (int off = 32; off > 0; off >>= 1) {
    s  += __shfl_xor(s, off);
    sq += __shfl_xor(sq, off);
  }
  __shared__ float ps[4], psq[4];
  int wave = tid >> 6;
  if ((tid & 63) == 0) { ps[wave] = s; psq[wave] = sq; }
  __syncthreads();
  float tot  = ps[0] + ps[1] + ps[2] + ps[3];
  float totq = psq[0] + psq[1] + psq[2] + psq[3];
  float mean = tot * (1.0f / D_MODEL);
  float var  = totq * (1.0f / D_MODEL) - mean * mean;
  float rs   = rsqrtf(var + 1e-5f);
  v4f gv = *(const v4f*)(gamma + tid * 4);
  v4f bv = *(const v4f*)(beta + tid * 4);
  half4h o;
#pragma unroll
  for (int i = 0; i < 4; ++i)
    o[i] = (_Float16)((xv[i] - mean) * rs * gv[i] + bv[i]);
  *(half4h*)(xn + (size_t)row * D_MODEL + tid * 4) = o;
}

// ------- fragize weights: W (K x N fp32) -> Bfrag[nt][kt][lane][8] fp16 -------
__global__ __launch_bounds__(256) void fragize_kernel(const float* __restrict__ W,
                                                      _Float16* __restrict__ Bf,
                                                      int N, int K) {
  int g = blockIdx.x * 256 + threadIdx.x;
  int lane = g & 63, tile = g >> 6;
  int ktiles = K >> 5;
  int kt = tile % ktiles, nt = tile / ktiles;
  int n  = nt * 16 + (lane & 15);
  int k0 = kt * 32 + (lane >> 4) * 8;
  half8 o;
#pragma unroll
  for (int j = 0; j < 8; ++j) o[j] = (_Float16)W[(size_t)(k0 + j) * N + n];
  *(half8*)(Bf + (size_t)g * 8) = o;
}

// -- 128x128 MFMA GEMM: A in 3-buffer LDS ring (counted vmcnt), B-frags from L2,
//    XCD-chunked block remap. MODE 0 epilogue: Q*(0.125*log2e), K planes (t,d);
//    V written DIRECTLY TRANSPOSED into Vt layout (d,t) -> vtrans kernel removed.
//    V store: t contiguous over r (m=..+quad*4+r) -> one 8B half4h per (mi,ni),
//    aligned (t0 mult of 4), never crossing batch bound (128|1024).
//    MODE 1: fp32 out + bias.
template <int MODE>
__global__ __launch_bounds__(256) void gemm_kernel(
    const _Float16* __restrict__ A, const _Float16* __restrict__ Bfrag,
    const float* __restrict__ bias, int M, int N, int K,
    float* __restrict__ outF,
    _Float16* __restrict__ Qd, _Float16* __restrict__ Kd, _Float16* __restrict__ Vt) {
  __shared__ _Float16 As[3][4096];   // 24 KB, triple-buffered A ring
  int tid = threadIdx.x;
  int wave = tid >> 6, lane = tid & 63;
  int l15 = lane & 15, quad = lane >> 4;
  int wm = (wave & 1) * 64, wn = (wave >> 1) * 64;
  // XCD-chunked remap (R8: +4.5% measured): xcd owns contiguous m-chunk; m fast.
  int lin = blockIdx.y * gridDim.x + blockIdx.x;
  int xcd = lin & 7, idx = lin >> 3;
  int nmc = gridDim.x >> 3;
  int m0 = (xcd * nmc + (idx % nmc)) * 128;
  int n0 = (idx / nmc) * 128;
  v4f zero = {0.f, 0.f, 0.f, 0.f};
  v4f acc[4][4];
#pragma unroll
  for (int i = 0; i < 4; ++i)
#pragma unroll
    for (int j = 0; j < 4; ++j) acc[i][j] = zero;

  int ar0 = tid >> 2;          // per-block row 0..63 (chunk 1: +64)
  int akc = (tid & 3) * 8;
  const _Float16* Ap = A + (size_t)(m0 + ar0) * K + akc;
  const int ktiles = K >> 5;
  const _Float16* Bp = Bfrag + (size_t)((n0 + wn) >> 4) * ktiles * 512 + lane * 8;

  // prologue: stage tile0 -> buf0, tile1 -> buf1 (4 loads in flight)
  {
    _Float16* w0 = &As[0][0] + wave * 512;
    load_lds16(Ap,                  w0);
    load_lds16(Ap + (size_t)64 * K, w0 + 2048);
    _Float16* w1 = &As[1][0] + wave * 512;
    load_lds16(Ap + 32,                  w1);
    load_lds16(Ap + 32 + (size_t)64 * K, w1 + 2048);
  }

  int cur = 0;
  for (int kt = 0; kt < ktiles; ++kt) {
    if (kt + 1 < ktiles) {
      asm volatile("s_waitcnt vmcnt(2)" ::: "memory");   // tile kt landed (mine)
    } else {
      asm volatile("s_waitcnt vmcnt(0)" ::: "memory");
    }
    __builtin_amdgcn_s_barrier();                        // everyone's tile kt landed
    __builtin_amdgcn_sched_barrier(0);
    // B-frags first: compiler's own wait before MFMA then leaves the newest
    // (stage) loads outstanding -> ring depth preserved.
    half8 bf[4];
#pragma unroll
    for (int ni = 0; ni < 4; ++ni)
      bf[ni] = *(const half8*)(Bp + ((size_t)ni * ktiles + kt) * 512);
    __builtin_amdgcn_sched_barrier(0);
    if (kt + 2 < ktiles) {   // stage tile kt+2 into the buffer last read at kt-1
      int stg = cur == 0 ? 2 : cur - 1;                  // (cur+2) mod 3
      _Float16* nx = &As[stg][0] + wave * 512;
      load_lds16(Ap + (kt + 2) * 32,                  nx);
      load_lds16(Ap + (kt + 2) * 32 + (size_t)64 * K, nx + 2048);
    }
    __builtin_amdgcn_sched_barrier(0);
    half8 af[4];
#pragma unroll
    for (int i = 0; i < 4; ++i)
      af[i] = *(const half8*)&As[cur][(wm + i * 16 + l15) * 32 + quad * 8];
#pragma unroll
    for (int mi = 0; mi < 4; ++mi)
#pragma unroll
      for (int ni = 0; ni < 4; ++ni)
        acc[mi][ni] = __builtin_amdgcn_mfma_f32_16x16x32_f16(af[mi], bf[ni], acc[mi][ni], 0, 0, 0);
    cur = cur == 2 ? 0 : cur + 1;
  }
  // epilogue: C layout row=quad*4+r, col=l15
  float bv[4];
#pragma unroll
  for (int ni = 0; ni < 4; ++ni) bv[ni] = bias[n0 + wn + ni * 16 + l15];
#pragma unroll
  for (int mi = 0; mi < 4; ++mi) {
#pragma unroll
    for (int ni = 0; ni < 4; ++ni) {
      int n = n0 + wn + ni * 16 + l15;
      if (MODE == 1) {
#pragma unroll
        for (int r = 0; r < 4; ++r) {
          int m = m0 + wm + mi * 16 + quad * 4 + r;
          outF[(size_t)m * N + n] = acc[mi][ni][r] + bv[ni];
        }
      } else {
        int h = (n >> 6) & 15, d = n & 63;
        if (n < 2048) {   // Q (scaled) / K, (b,h,t,d) layout — wave-uniform branch
#pragma unroll
          for (int r = 0; r < 4; ++r) {
            int m = m0 + wm + mi * 16 + quad * 4 + r;
            int b = m >> 10, t = m & 1023;
            size_t idx2 = ((size_t)(b * NHEAD + h) * T_SEQ + t) * HDIM + d;
            float v = acc[mi][ni][r] + bv[ni];
            // 0.125 * log2(e): softmax runs in exp2 domain
            if (n < 1024) Qd[idx2] = (_Float16)(v * 0.18033688f);
            else          Kd[idx2] = (_Float16)v;
          }
        } else {          // V: direct transposed store, (b,h,d,t) layout
          int mb = m0 + wm + mi * 16 + quad * 4;
          int b = mb >> 10, t = mb & 1023;
          half4h vk;
#pragma unroll
          for (int r = 0; r < 4; ++r) vk[r] = (_Float16)(acc[mi][ni][r] + bv[ni]);
          *(half4h*)&Vt[((size_t)(b * NHEAD + h) * HDIM + d) * T_SEQ + t] = vk;
        }
      }
    }
  }
}

// ------- flash attention: 8 waves / 128 q-rows per block, 64-key tiles ------
// S^T = K Q^T: lane owns ONE q-row (col=l15), 16 keys in regs. O^T = V^T P^T.
// K/V double-buffered in LDS; tile jt+1 prefetched async during compute of jt;
// per-wave counted vmcnt(2) + raw s_barrier pair. Heavy q-tiles first.
__global__ __launch_bounds__(512) void attn_kernel(const _Float16* __restrict__ Qg,
                                                   const _Float16* __restrict__ Kk,
                                                   const _Float16* __restrict__ Vt,
                                                   const int* __restrict__ x_lens,
                                                   _Float16* __restrict__ att) {
  __shared__ _Float16 Ks[2][2][2048];   // [buf][d-half][key*32 + chunk]
  __shared__ _Float16 Vs[2][2][2048];   // [buf][key-half][d*32 + chunk]
  __shared__ _Float16 Pb[8][16 * 72];   // per-wave roundtrip: [q_local][key or d]
  int blk = blockIdx.x;
  int qt = 7 - (blk >> 7);    // heavy-first: work/block ~ qt; dispatch big ones early
  int bh = blk & 127;
  int h  = bh & 15;
  int b  = bh >> 4;
  int t0 = qt * 128;
  int len = x_lens[b];
  int tid = threadIdx.x;
  int wave = tid >> 6, lane = tid & 63;
  int l15 = lane & 15, quad = lane >> 4;
  size_t plane = (size_t)(b * NHEAD + h) * (T_SEQ * HDIM);
  int qrow = t0 + wave * 16;
  int qabs = qrow + l15;
  const _Float16* Qp = Qg + plane + (size_t)qabs * HDIM + quad * 8;
  half8 qf0 = *(const half8*)Qp;          // B-frag: Q[q=l15][d=quad*8+j]
  half8 qf1 = *(const half8*)(Qp + 32);
  v4f zero = {0.f, 0.f, 0.f, 0.f};
  float m_i = -1e30f, l_i = 0.f;          // per-lane: one q-row
  v4f Ov[4];                              // O^T C-layout: row d=16nt+quad*4+r, col q=l15
#pragma unroll
  for (int nt = 0; nt < 4; ++nt) Ov[nt] = zero;

  int jmaxb = min(t0 + 127, len - 1);
  int ntile = (jmaxb >> 6) + 1;
  int wjmax = min(qrow + 15, len - 1);

  // staging: 16 units of 1KB; wave w handles units w*2, w*2+1
  const _Float16* src[2];
  _Float16* dst0[2];   // destination in buffer 0; buffer b: +b*4096 halves
  int strd[2];
#pragma unroll
  for (int i = 0; i < 2; ++i) {
    int u = wave * 2 + i;
    int q = u & 3, hf = (u >> 2) & 1;
    if (u < 8) {
      src[i] = Kk + plane + (size_t)(q * 16 + (lane >> 2)) * HDIM + hf * 32 + (lane & 3) * 8;
      dst0[i] = &Ks[0][hf][0] + q * 512;
      strd[i] = 64 * HDIM;
    } else {
      src[i] = Vt + plane + (size_t)(q * 16 + (lane >> 2)) * T_SEQ + hf * 32 + (lane & 3) * 8;
      dst0[i] = &Vs[0][hf][0] + q * 512;
      strd[i] = 64;
    }
  }

  // prologue: stage tile 0 -> buf 0
#pragma unroll
  for (int i = 0; i < 2; ++i) { load_lds16(src[i], dst0[i]); src[i] += strd[i]; }

  for (int jt = 0; jt < ntile; ++jt) {
    int j0 = jt * 64;
    int cur = jt & 1;
    __builtin_amdgcn_s_barrier();          // all waves done reading buf[cur^1] (tile jt-1)
    if (jt + 1 < ntile) {                  // prefetch tile jt+1 into buf[cur^1]
#pragma unroll
      for (int i = 0; i < 2; ++i) {
        load_lds16(src[i], dst0[i] + (cur ^ 1) * 4096);
        src[i] += strd[i];
      }
      asm volatile("s_waitcnt vmcnt(2)" ::: "memory");   // my tile-jt loads landed
    } else {
      asm volatile("s_waitcnt vmcnt(0)" ::: "memory");
    }
    __builtin_amdgcn_s_barrier();          // everyone's tile-jt loads landed
    __builtin_amdgcn_sched_barrier(0);
    if (j0 <= wjmax) {
      v4f s[4];
      __builtin_amdgcn_s_setprio(1);
#pragma unroll
      for (int nt = 0; nt < 4; ++nt) {
        s[nt] = zero;
        half8 k0 = *(const half8*)&Ks[cur][0][(nt * 16 + l15) * 32 + quad * 8];
        half8 k1 = *(const half8*)&Ks[cur][1][(nt * 16 + l15) * 32 + quad * 8];
        s[nt] = __builtin_amdgcn_mfma_f32_16x16x32_f16(k0, qf0, s[nt], 0, 0, 0);
        s[nt] = __builtin_amdgcn_mfma_f32_16x16x32_f16(k1, qf1, s[nt], 0, 0, 0);
      }
      __builtin_amdgcn_s_setprio(0);
      float mnew = m_i;
      bool full = (j0 + 63 <= qrow) && (j0 + 63 < len);
      if (full) {
#pragma unroll
        for (int nt = 0; nt < 4; ++nt)
#pragma unroll
          for (int r = 0; r < 4; ++r)
            mnew = fmaxf(mnew, s[nt][r]);
      } else {
#pragma unroll
        for (int nt = 0; nt < 4; ++nt) {
#pragma unroll
          for (int r = 0; r < 4; ++r) {
            int key = j0 + nt * 16 + quad * 4 + r;
            float v = (key <= qabs && key < len) ? s[nt][r] : -1e30f;
            s[nt][r] = v;
            mnew = fmaxf(mnew, v);
          }
        }
      }
      mnew = fmaxf(mnew, __shfl_xor(mnew, 16));
      mnew = fmaxf(mnew, __shfl_xor(mnew, 32));
      float alpha = exp2f(m_i - mnew);
      m_i = mnew;
      float rsum = 0.f;
#pragma unroll
      for (int nt = 0; nt < 4; ++nt)
#pragma unroll
        for (int r = 0; r < 4; ++r) {
          float p = exp2f(s[nt][r] - mnew);
          s[nt][r] = p;
          rsum += p;
        }
      rsum += __shfl_xor(rsum, 16);
      rsum += __shfl_xor(rsum, 32);
      l_i = l_i * alpha + rsum;
#pragma unroll
      for (int nt = 0; nt < 4; ++nt)
#pragma unroll
        for (int r = 0; r < 4; ++r) Ov[nt][r] *= alpha;
#pragma unroll
      for (int nt = 0; nt < 4; ++nt) {
        half4h pk;
#pragma unroll
        for (int r = 0; r < 4; ++r) pk[r] = (_Float16)s[nt][r];
        *(half4h*)&Pb[wave][l15 * 72 + nt * 16 + quad * 4] = pk;
      }
      asm volatile("s_waitcnt lgkmcnt(0)" ::: "memory");
      half8 pf0 = *(const half8*)&Pb[wave][l15 * 72 + quad * 8];
      half8 pf1 = *(const half8*)&Pb[wave][l15 * 72 + 32 + quad * 8];
      __builtin_amdgcn_s_setprio(1);
#pragma unroll
      for (int nt = 0; nt < 4; ++nt) {
        half8 v0 = *(const half8*)&Vs[cur][0][(nt * 16 + l15) * 32 + quad * 8];
        half8 v1 = *(const half8*)&Vs[cur][1][(nt * 16 + l15) * 32 + quad * 8];
        Ov[nt] = __builtin_amdgcn_mfma_f32_16x16x32_f16(v0, pf0, Ov[nt], 0, 0, 0);
        Ov[nt] = __builtin_amdgcn_mfma_f32_16x16x32_f16(v1, pf1, Ov[nt], 0, 0, 0);
      }
      __builtin_amdgcn_s_setprio(0);
    }
  }
  // epilogue: O^T regs -> Pb[q_local][d] -> coalesced row-major stores
  float inv = 1.0f / l_i;
#pragma unroll
  for (int nt = 0; nt < 4; ++nt) {
    half4h ok;
#pragma unroll
    for (int r = 0; r < 4; ++r) ok[r] = (_Float16)(Ov[nt][r] * inv);
    *(half4h*)&Pb[wave][l15 * 72 + nt * 16 + quad * 4] = ok;
  }
  asm volatile("s_waitcnt lgkmcnt(0)" ::: "memory");
  int r0 = lane >> 3, c0 = (lane & 7) * 8;
  half8 o0 = *(const half8*)&Pb[wave][r0 * 72 + c0];
  half8 o1 = *(const half8*)&Pb[wave][(r0 + 8) * 72 + c0];
  *(half8*)&att[((size_t)(b * T_SEQ) + qrow + r0) * D_MODEL + h * HDIM + c0] = o0;
  *(half8*)&att[((size_t)(b * T_SEQ) + qrow + r0 + 8) * D_MODEL + h * HDIM + c0] = o1;
}

extern "C" void kernel_launch(void* const* d_in, const int* in_sizes, int n_in,
                              void* d_out, int out_size, void* d_ws, size_t ws_size,
                              hipStream_t stream) {
  const float* x        = (const float*)d_in[0];
  const int*   x_lens   = (const int*)d_in[1];
  const float* ln_gamma = (const float*)d_in[2];
  const float* ln_beta  = (const float*)d_in[3];
  const float* w_qkv    = (const float*)d_in[4];
  const float* b_qkv    = (const float*)d_in[5];
  const float* w_out    = (const float*)d_in[6];
  const float* b_out    = (const float*)d_in[7];
  float* out = (float*)d_out;

  char* w = (char*)d_ws;
  _Float16* xn    = (_Float16*)w; w += (size_t)8192 * 1024 * 2;
  _Float16* BfQKV = (_Float16*)w; w += (size_t)3072 * 1024 * 2;
  _Float16* BfOut = (_Float16*)w; w += (size_t)1024 * 1024 * 2;
  _Float16* Qd    = (_Float16*)w; w += (size_t)8192 * 1024 * 2;
  _Float16* Kd    = (_Float16*)w; w += (size_t)8192 * 1024 * 2;
  _Float16* Vt    = (_Float16*)w; w += (size_t)8192 * 1024 * 2;   // (b,h,d,t) — written directly by gemm<0>
  _Float16* att   = (_Float16*)w; w += (size_t)8192 * 1024 * 2;

  fragize_kernel<<<(3072 * 1024 / 8) / 256, 256, 0, stream>>>(w_qkv, BfQKV, 3072, 1024);
  fragize_kernel<<<(1024 * 1024 / 8) / 256, 256, 0, stream>>>(w_out, BfOut, 1024, 1024);
  ln_kernel<<<8192, 256, 0, stream>>>(x, ln_gamma, ln_beta, xn);
  gemm_kernel<0><<<dim3(8192 / 128, 3072 / 128), 256, 0, stream>>>(
      xn, BfQKV, b_qkv, 8192, 3072, 1024, nullptr, Qd, Kd, Vt);
  attn_kernel<<<1024, 512, 0, stream>>>(Qd, Kd, Vt, x_lens, att);
  gemm_kernel<1><<<dim3(8192 / 128, 1024 / 128), 256, 0, stream>>>(
      att, BfOut, b_out, 8192, 1024, 1024, out, nullptr, nullptr, nullptr);
}

// Round 12
// 236.279 us; speedup vs baseline: 1.0363x; 1.0363x over previous
//
#include <hip/hip_runtime.h>

#define D_MODEL 1024
#define T_SEQ   1024
#define BATCH   8
#define NHEAD   16
#define HDIM    64

typedef float      v4f   __attribute__((ext_vector_type(4)));
typedef _Float16   half8 __attribute__((ext_vector_type(8)));
typedef _Float16   half4h __attribute__((ext_vector_type(4)));
typedef unsigned int ui4 __attribute__((ext_vector_type(4)));

// async global->LDS, 16B per lane, dest = wave-uniform base + lane*16
__device__ __forceinline__ void load_lds16(const _Float16* g, _Float16* l) {
  __builtin_amdgcn_global_load_lds(
      (const __attribute__((address_space(1))) unsigned int*)g,
      (__attribute__((address_space(3))) unsigned int*)l, 16, 0, 0);
}

// ---------------- LayerNorm (fp32 in) -> fp16 xn ----------------
__global__ __launch_bounds__(256) void ln_kernel(const float* __restrict__ x,
                                                 const float* __restrict__ gamma,
                                                 const float* __restrict__ beta,
                                                 _Float16* __restrict__ xn) {
  int row = blockIdx.x;
  int tid = threadIdx.x;
  const float* xr = x + (size_t)row * D_MODEL;
  v4f xv = *(const v4f*)(xr + tid * 4);
  float s  = xv[0] + xv[1] + xv[2] + xv[3];
  float sq = xv[0]*xv[0] + xv[1]*xv[1] + xv[2]*xv[2] + xv[3]*xv[3];
#pragma unroll
  for (int off = 32; off > 0; off >>= 1) {
    s  += __shfl_xor(s, off);
    sq += __shfl_xor(sq, off);
  }
  __shared__ float ps[4], psq[4];
  int wave = tid >> 6;
  if ((tid & 63) == 0) { ps[wave] = s; psq[wave] = sq; }
  __syncthreads();
  float tot  = ps[0] + ps[1] + ps[2] + ps[3];
  float totq = psq[0] + psq[1] + psq[2] + psq[3];
  float mean = tot * (1.0f / D_MODEL);
  float var  = totq * (1.0f / D_MODEL) - mean * mean;
  float rs   = rsqrtf(var + 1e-5f);
  v4f gv = *(const v4f*)(gamma + tid * 4);
  v4f bv = *(const v4f*)(beta + tid * 4);
  half4h o;
#pragma unroll
  for (int i = 0; i < 4; ++i)
    o[i] = (_Float16)((xv[i] - mean) * rs * gv[i] + bv[i]);
  *(half4h*)(xn + (size_t)row * D_MODEL + tid * 4) = o;
}

// ------- fragize weights: W (K x N fp32) -> Bfrag[nt][kt][lane][8] fp16 -------
__global__ __launch_bounds__(256) void fragize_kernel(const float* __restrict__ W,
                                                      _Float16* __restrict__ Bf,
                                                      int N, int K) {
  int g = blockIdx.x * 256 + threadIdx.x;
  int lane = g & 63, tile = g >> 6;
  int ktiles = K >> 5;
  int kt = tile % ktiles, nt = tile / ktiles;
  int n  = nt * 16 + (lane & 15);
  int k0 = kt * 32 + (lane >> 4) * 8;
  half8 o;
#pragma unroll
  for (int j = 0; j < 8; ++j) o[j] = (_Float16)W[(size_t)(k0 + j) * N + n];
  *(half8*)(Bf + (size_t)g * 8) = o;
}

// -- 128x128 MFMA GEMM: A in 3-buffer LDS ring (counted vmcnt), B-frags from L2,
//    XCD-chunked block remap. MODE 0 epilogue: Q*(0.125*log2e), K planes (t,d);
//    V written DIRECTLY TRANSPOSED into Vt layout (d,t).  MODE 1: fp32 out + bias.
template <int MODE>
__global__ __launch_bounds__(256) void gemm_kernel(
    const _Float16* __restrict__ A, const _Float16* __restrict__ Bfrag,
    const float* __restrict__ bias, int M, int N, int K,
    float* __restrict__ outF,
    _Float16* __restrict__ Qd, _Float16* __restrict__ Kd, _Float16* __restrict__ Vt) {
  __shared__ _Float16 As[3][4096];   // 24 KB, triple-buffered A ring
  int tid = threadIdx.x;
  int wave = tid >> 6, lane = tid & 63;
  int l15 = lane & 15, quad = lane >> 4;
  int wm = (wave & 1) * 64, wn = (wave >> 1) * 64;
  // XCD-chunked remap (R8: +4.5% measured): xcd owns contiguous m-chunk; m fast.
  int lin = blockIdx.y * gridDim.x + blockIdx.x;
  int xcd = lin & 7, idx = lin >> 3;
  int nmc = gridDim.x >> 3;
  int m0 = (xcd * nmc + (idx % nmc)) * 128;
  int n0 = (idx / nmc) * 128;
  v4f zero = {0.f, 0.f, 0.f, 0.f};
  v4f acc[4][4];
#pragma unroll
  for (int i = 0; i < 4; ++i)
#pragma unroll
    for (int j = 0; j < 4; ++j) acc[i][j] = zero;

  int ar0 = tid >> 2;          // per-block row 0..63 (chunk 1: +64)
  int akc = (tid & 3) * 8;
  const _Float16* Ap = A + (size_t)(m0 + ar0) * K + akc;
  const int ktiles = K >> 5;
  const _Float16* Bp = Bfrag + (size_t)((n0 + wn) >> 4) * ktiles * 512 + lane * 8;

  // prologue: stage tile0 -> buf0, tile1 -> buf1 (4 loads in flight)
  {
    _Float16* w0 = &As[0][0] + wave * 512;
    load_lds16(Ap,                  w0);
    load_lds16(Ap + (size_t)64 * K, w0 + 2048);
    _Float16* w1 = &As[1][0] + wave * 512;
    load_lds16(Ap + 32,                  w1);
    load_lds16(Ap + 32 + (size_t)64 * K, w1 + 2048);
  }

  int cur = 0;
  for (int kt = 0; kt < ktiles; ++kt) {
    if (kt + 1 < ktiles) {
      asm volatile("s_waitcnt vmcnt(2)" ::: "memory");   // tile kt landed (mine)
    } else {
      asm volatile("s_waitcnt vmcnt(0)" ::: "memory");
    }
    __builtin_amdgcn_s_barrier();                        // everyone's tile kt landed
    __builtin_amdgcn_sched_barrier(0);
    // B-frags first: compiler's own wait before MFMA then leaves the newest
    // (stage) loads outstanding -> ring depth preserved.
    half8 bf[4];
#pragma unroll
    for (int ni = 0; ni < 4; ++ni)
      bf[ni] = *(const half8*)(Bp + ((size_t)ni * ktiles + kt) * 512);
    __builtin_amdgcn_sched_barrier(0);
    if (kt + 2 < ktiles) {   // stage tile kt+2 into the buffer last read at kt-1
      int stg = cur == 0 ? 2 : cur - 1;                  // (cur+2) mod 3
      _Float16* nx = &As[stg][0] + wave * 512;
      load_lds16(Ap + (kt + 2) * 32,                  nx);
      load_lds16(Ap + (kt + 2) * 32 + (size_t)64 * K, nx + 2048);
    }
    __builtin_amdgcn_sched_barrier(0);
    half8 af[4];
#pragma unroll
    for (int i = 0; i < 4; ++i)
      af[i] = *(const half8*)&As[cur][(wm + i * 16 + l15) * 32 + quad * 8];
#pragma unroll
    for (int mi = 0; mi < 4; ++mi)
#pragma unroll
      for (int ni = 0; ni < 4; ++ni)
        acc[mi][ni] = __builtin_amdgcn_mfma_f32_16x16x32_f16(af[mi], bf[ni], acc[mi][ni], 0, 0, 0);
    cur = cur == 2 ? 0 : cur + 1;
  }
  // epilogue: C layout row=quad*4+r, col=l15
  float bv[4];
#pragma unroll
  for (int ni = 0; ni < 4; ++ni) bv[ni] = bias[n0 + wn + ni * 16 + l15];
#pragma unroll
  for (int mi = 0; mi < 4; ++mi) {
#pragma unroll
    for (int ni = 0; ni < 4; ++ni) {
      int n = n0 + wn + ni * 16 + l15;
      if (MODE == 1) {
#pragma unroll
        for (int r = 0; r < 4; ++r) {
          int m = m0 + wm + mi * 16 + quad * 4 + r;
          outF[(size_t)m * N + n] = acc[mi][ni][r] + bv[ni];
        }
      } else {
        int h = (n >> 6) & 15, d = n & 63;
        if (n < 2048) {   // Q (scaled) / K, (b,h,t,d) layout — wave-uniform branch
#pragma unroll
          for (int r = 0; r < 4; ++r) {
            int m = m0 + wm + mi * 16 + quad * 4 + r;
            int b = m >> 10, t = m & 1023;
            size_t idx2 = ((size_t)(b * NHEAD + h) * T_SEQ + t) * HDIM + d;
            float v = acc[mi][ni][r] + bv[ni];
            // 0.125 * log2(e): softmax runs in exp2 domain
            if (n < 1024) Qd[idx2] = (_Float16)(v * 0.18033688f);
            else          Kd[idx2] = (_Float16)v;
          }
        } else {          // V: direct transposed store, (b,h,d,t) layout
          int mb = m0 + wm + mi * 16 + quad * 4;
          int b = mb >> 10, t = mb & 1023;
          half4h vk;
#pragma unroll
          for (int r = 0; r < 4; ++r) vk[r] = (_Float16)(acc[mi][ni][r] + bv[ni]);
          *(half4h*)&Vt[((size_t)(b * NHEAD + h) * HDIM + d) * T_SEQ + t] = vk;
        }
      }
    }
  }
}

// ------- flash attention: 8 waves / 128 q-rows per block, 64-key tiles ------
// S^T = K Q^T: lane owns ONE q-row (col=l15), 16 keys in regs. O^T = V^T P^T.
// K/V in a 3-BUFFER LDS ring: tile jt+2 staged during compute of jt -> stage->use
// distance ~2 tiles (covers HBM-class latency). Per-wave counted vmcnt(4) + raw
// s_barrier pair (WAR: buf[(jt+2)%3] last read at jt-1, proven by top barrier).
// LDS 66KB -> 2 blocks/CU. Heavy q-tiles dispatch first.
__global__ __launch_bounds__(512) void attn_kernel(const _Float16* __restrict__ Qg,
                                                   const _Float16* __restrict__ Kk,
                                                   const _Float16* __restrict__ Vt,
                                                   const int* __restrict__ x_lens,
                                                   _Float16* __restrict__ att) {
  __shared__ _Float16 Ks[3][2][2048];   // [buf][d-half][key*32 + chunk]
  __shared__ _Float16 Vs[3][2][2048];   // [buf][key-half][d*32 + chunk]
  __shared__ _Float16 Pb[8][16 * 72];   // per-wave roundtrip: [q_local][key or d]
  int blk = blockIdx.x;
  int qt = 7 - (blk >> 7);    // heavy-first: work/block ~ qt; dispatch big ones early
  int bh = blk & 127;
  int h  = bh & 15;
  int b  = bh >> 4;
  int t0 = qt * 128;
  int len = x_lens[b];
  int tid = threadIdx.x;
  int wave = tid >> 6, lane = tid & 63;
  int l15 = lane & 15, quad = lane >> 4;
  size_t plane = (size_t)(b * NHEAD + h) * (T_SEQ * HDIM);
  int qrow = t0 + wave * 16;
  int qabs = qrow + l15;
  const _Float16* Qp = Qg + plane + (size_t)qabs * HDIM + quad * 8;
  half8 qf0 = *(const half8*)Qp;          // B-frag: Q[q=l15][d=quad*8+j]
  half8 qf1 = *(const half8*)(Qp + 32);
  v4f zero = {0.f, 0.f, 0.f, 0.f};
  float m_i = -1e30f, l_i = 0.f;          // per-lane: one q-row
  v4f Ov[4];                              // O^T C-layout: row d=16nt+quad*4+r, col q=l15
#pragma unroll
  for (int nt = 0; nt < 4; ++nt) Ov[nt] = zero;

  int jmaxb = min(t0 + 127, len - 1);
  int ntile = (jmaxb >> 6) + 1;
  int wjmax = min(qrow + 15, len - 1);

  // staging: 16 units of 1KB; wave w handles units w*2, w*2+1
  const _Float16* src[2];
  _Float16* dst0[2];   // destination in buffer 0; buffer b: +b*4096 halves
  int strd[2];
#pragma unroll
  for (int i = 0; i < 2; ++i) {
    int u = wave * 2 + i;
    int q = u & 3, hf = (u >> 2) & 1;
    if (u < 8) {
      src[i] = Kk + plane + (size_t)(q * 16 + (lane >> 2)) * HDIM + hf * 32 + (lane & 3) * 8;
      dst0[i] = &Ks[0][hf][0] + q * 512;
      strd[i] = 64 * HDIM;
    } else {
      src[i] = Vt + plane + (size_t)(q * 16 + (lane >> 2)) * T_SEQ + hf * 32 + (lane & 3) * 8;
      dst0[i] = &Vs[0][hf][0] + q * 512;
      strd[i] = 64;
    }
  }

  // prologue: stage tile 0 -> buf 0, tile 1 -> buf 1
#pragma unroll
  for (int i = 0; i < 2; ++i) { load_lds16(src[i], dst0[i]); src[i] += strd[i]; }
  if (ntile > 1) {
#pragma unroll
    for (int i = 0; i < 2; ++i) { load_lds16(src[i], dst0[i] + 4096); src[i] += strd[i]; }
  }

  int cur = 0;
  for (int jt = 0; jt < ntile; ++jt) {
    int j0 = jt * 64;
    __builtin_amdgcn_s_barrier();          // all waves done compute of jt-1
    if (jt + 2 < ntile) {                  // stage tile jt+2 into buf[(jt+2)%3]
      int stg = cur == 0 ? 2 : cur - 1;    // (cur+2) mod 3
#pragma unroll
      for (int i = 0; i < 2; ++i) {
        load_lds16(src[i], dst0[i] + stg * 4096);
        src[i] += strd[i];
      }
      asm volatile("s_waitcnt vmcnt(4)" ::: "memory");   // my tile-jt loads landed
    } else if (jt + 1 < ntile) {
      asm volatile("s_waitcnt vmcnt(2)" ::: "memory");
    } else {
      asm volatile("s_waitcnt vmcnt(0)" ::: "memory");
    }
    __builtin_amdgcn_s_barrier();          // everyone's tile-jt loads landed
    __builtin_amdgcn_sched_barrier(0);
    if (j0 <= wjmax) {
      v4f s[4];
      __builtin_amdgcn_s_setprio(1);
#pragma unroll
      for (int nt = 0; nt < 4; ++nt) {
        s[nt] = zero;
        half8 k0 = *(const half8*)&Ks[cur][0][(nt * 16 + l15) * 32 + quad * 8];
        half8 k1 = *(const half8*)&Ks[cur][1][(nt * 16 + l15) * 32 + quad * 8];
        s[nt] = __builtin_amdgcn_mfma_f32_16x16x32_f16(k0, qf0, s[nt], 0, 0, 0);
        s[nt] = __builtin_amdgcn_mfma_f32_16x16x32_f16(k1, qf1, s[nt], 0, 0, 0);
      }
      __builtin_amdgcn_s_setprio(0);
      float mnew = m_i;
      bool full = (j0 + 63 <= qrow) && (j0 + 63 < len);
      if (full) {
#pragma unroll
        for (int nt = 0; nt < 4; ++nt)
#pragma unroll
          for (int r = 0; r < 4; ++r)
            mnew = fmaxf(mnew, s[nt][r]);
      } else {
#pragma unroll
        for (int nt = 0; nt < 4; ++nt) {
#pragma unroll
          for (int r = 0; r < 4; ++r) {
            int key = j0 + nt * 16 + quad * 4 + r;
            float v = (key <= qabs && key < len) ? s[nt][r] : -1e30f;
            s[nt][r] = v;
            mnew = fmaxf(mnew, v);
          }
        }
      }
      mnew = fmaxf(mnew, __shfl_xor(mnew, 16));
      mnew = fmaxf(mnew, __shfl_xor(mnew, 32));
      float alpha = exp2f(m_i - mnew);
      m_i = mnew;
      float rsum = 0.f;
#pragma unroll
      for (int nt = 0; nt < 4; ++nt)
#pragma unroll
        for (int r = 0; r < 4; ++r) {
          float p = exp2f(s[nt][r] - mnew);
          s[nt][r] = p;
          rsum += p;
        }
      rsum += __shfl_xor(rsum, 16);
      rsum += __shfl_xor(rsum, 32);
      l_i = l_i * alpha + rsum;
#pragma unroll
      for (int nt = 0; nt < 4; ++nt)
#pragma unroll
        for (int r = 0; r < 4; ++r) Ov[nt][r] *= alpha;
#pragma unroll
      for (int nt = 0; nt < 4; ++nt) {
        half4h pk;
#pragma unroll
        for (int r = 0; r < 4; ++r) pk[r] = (_Float16)s[nt][r];
        *(half4h*)&Pb[wave][l15 * 72 + nt * 16 + quad * 4] = pk;
      }
      asm volatile("s_waitcnt lgkmcnt(0)" ::: "memory");
      half8 pf0 = *(const half8*)&Pb[wave][l15 * 72 + quad * 8];
      half8 pf1 = *(const half8*)&Pb[wave][l15 * 72 + 32 + quad * 8];
      __builtin_amdgcn_s_setprio(1);
#pragma unroll
      for (int nt = 0; nt < 4; ++nt) {
        half8 v0 = *(const half8*)&Vs[cur][0][(nt * 16 + l15) * 32 + quad * 8];
        half8 v1 = *(const half8*)&Vs[cur][1][(nt * 16 + l15) * 32 + quad * 8];
        Ov[nt] = __builtin_amdgcn_mfma_f32_16x16x32_f16(v0, pf0, Ov[nt], 0, 0, 0);
        Ov[nt] = __builtin_amdgcn_mfma_f32_16x16x32_f16(v1, pf1, Ov[nt], 0, 0, 0);
      }
      __builtin_amdgcn_s_setprio(0);
    }
    cur = cur == 2 ? 0 : cur + 1;
  }
  // epilogue: O^T regs -> Pb[q_local][d] -> coalesced row-major stores
  float inv = 1.0f / l_i;
#pragma unroll
  for (int nt = 0; nt < 4; ++nt) {
    half4h ok;
#pragma unroll
    for (int r = 0; r < 4; ++r) ok[r] = (_Float16)(Ov[nt][r] * inv);
    *(half4h*)&Pb[wave][l15 * 72 + nt * 16 + quad * 4] = ok;
  }
  asm volatile("s_waitcnt lgkmcnt(0)" ::: "memory");
  int r0 = lane >> 3, c0 = (lane & 7) * 8;
  half8 o0 = *(const half8*)&Pb[wave][r0 * 72 + c0];
  half8 o1 = *(const half8*)&Pb[wave][(r0 + 8) * 72 + c0];
  *(half8*)&att[((size_t)(b * T_SEQ) + qrow + r0) * D_MODEL + h * HDIM + c0] = o0;
  *(half8*)&att[((size_t)(b * T_SEQ) + qrow + r0 + 8) * D_MODEL + h * HDIM + c0] = o1;
}

extern "C" void kernel_launch(void* const* d_in, const int* in_sizes, int n_in,
                              void* d_out, int out_size, void* d_ws, size_t ws_size,
                              hipStream_t stream) {
  const float* x        = (const float*)d_in[0];
  const int*   x_lens   = (const int*)d_in[1];
  const float* ln_gamma = (const float*)d_in[2];
  const float* ln_beta  = (const float*)d_in[3];
  const float* w_qkv    = (const float*)d_in[4];
  const float* b_qkv    = (const float*)d_in[5];
  const float* w_out    = (const float*)d_in[6];
  const float* b_out    = (const float*)d_in[7];
  float* out = (float*)d_out;

  char* w = (char*)d_ws;
  _Float16* xn    = (_Float16*)w; w += (size_t)8192 * 1024 * 2;
  _Float16* BfQKV = (_Float16*)w; w += (size_t)3072 * 1024 * 2;
  _Float16* BfOut = (_Float16*)w; w += (size_t)1024 * 1024 * 2;
  _Float16* Qd    = (_Float16*)w; w += (size_t)8192 * 1024 * 2;
  _Float16* Kd    = (_Float16*)w; w += (size_t)8192 * 1024 * 2;
  _Float16* Vt    = (_Float16*)w; w += (size_t)8192 * 1024 * 2;   // (b,h,d,t) — written directly by gemm<0>
  _Float16* att   = (_Float16*)w; w += (size_t)8192 * 1024 * 2;

  fragize_kernel<<<(3072 * 1024 / 8) / 256, 256, 0, stream>>>(w_qkv, BfQKV, 3072, 1024);
  fragize_kernel<<<(1024 * 1024 / 8) / 256, 256, 0, stream>>>(w_out, BfOut, 1024, 1024);
  ln_kernel<<<8192, 256, 0, stream>>>(x, ln_gamma, ln_beta, xn);
  gemm_kernel<0><<<dim3(8192 / 128, 3072 / 128), 256, 0, stream>>>(
      xn, BfQKV, b_qkv, 8192, 3072, 1024, nullptr, Qd, Kd, Vt);
  attn_kernel<<<1024, 512, 0, stream>>>(Qd, Kd, Vt, x_lens, att);
  gemm_kernel<1><<<dim3(8192 / 128, 1024 / 128), 256, 0, stream>>>(
      att, BfOut, b_out, 8192, 1024, 1024, out, nullptr, nullptr, nullptr);
}

// Round 13
// 235.744 us; speedup vs baseline: 1.0386x; 1.0023x over previous
//
#include <hip/hip_runtime.h>

#define D_MODEL 1024
#define T_SEQ   1024
#define BATCH   8
#define NHEAD   16
#define HDIM    64

typedef float      v4f   __attribute__((ext_vector_type(4)));
typedef _Float16   half8 __attribute__((ext_vector_type(8)));
typedef _Float16   half4h __attribute__((ext_vector_type(4)));
typedef unsigned int ui4 __attribute__((ext_vector_type(4)));

// async global->LDS, 16B per lane, dest = wave-uniform base + lane*16
__device__ __forceinline__ void load_lds16(const _Float16* g, _Float16* l) {
  __builtin_amdgcn_global_load_lds(
      (const __attribute__((address_space(1))) unsigned int*)g,
      (__attribute__((address_space(3))) unsigned int*)l, 16, 0, 0);
}

// ---------------- LayerNorm (fp32 in) -> fp16 xn ----------------
__global__ __launch_bounds__(256) void ln_kernel(const float* __restrict__ x,
                                                 const float* __restrict__ gamma,
                                                 const float* __restrict__ beta,
                                                 _Float16* __restrict__ xn) {
  int row = blockIdx.x;
  int tid = threadIdx.x;
  const float* xr = x + (size_t)row * D_MODEL;
  v4f xv = *(const v4f*)(xr + tid * 4);
  float s  = xv[0] + xv[1] + xv[2] + xv[3];
  float sq = xv[0]*xv[0] + xv[1]*xv[1] + xv[2]*xv[2] + xv[3]*xv[3];
#pragma unroll
  for (int off = 32; off > 0; off >>= 1) {
    s  += __shfl_xor(s, off);
    sq += __shfl_xor(sq, off);
  }
  __shared__ float ps[4], psq[4];
  int wave = tid >> 6;
  if ((tid & 63) == 0) { ps[wave] = s; psq[wave] = sq; }
  __syncthreads();
  float tot  = ps[0] + ps[1] + ps[2] + ps[3];
  float totq = psq[0] + psq[1] + psq[2] + psq[3];
  float mean = tot * (1.0f / D_MODEL);
  float var  = totq * (1.0f / D_MODEL) - mean * mean;
  float rs   = rsqrtf(var + 1e-5f);
  v4f gv = *(const v4f*)(gamma + tid * 4);
  v4f bv = *(const v4f*)(beta + tid * 4);
  half4h o;
#pragma unroll
  for (int i = 0; i < 4; ++i)
    o[i] = (_Float16)((xv[i] - mean) * rs * gv[i] + bv[i]);
  *(half4h*)(xn + (size_t)row * D_MODEL + tid * 4) = o;
}

// ------- fragize weights: W (K x N fp32) -> Bfrag[nt][kt][lane][8] fp16 -------
__global__ __launch_bounds__(256) void fragize_kernel(const float* __restrict__ W,
                                                      _Float16* __restrict__ Bf,
                                                      int N, int K) {
  int g = blockIdx.x * 256 + threadIdx.x;
  int lane = g & 63, tile = g >> 6;
  int ktiles = K >> 5;
  int kt = tile % ktiles, nt = tile / ktiles;
  int n  = nt * 16 + (lane & 15);
  int k0 = kt * 32 + (lane >> 4) * 8;
  half8 o;
#pragma unroll
  for (int j = 0; j < 8; ++j) o[j] = (_Float16)W[(size_t)(k0 + j) * N + n];
  *(half8*)(Bf + (size_t)g * 8) = o;
}

// -- 128x128 MFMA GEMM: A in 3-buffer LDS ring (counted vmcnt), B-frags from L2,
//    XCD-chunked block remap. MODE 0 epilogue: Q*(0.125*log2e), K planes (t,d);
//    V written DIRECTLY TRANSPOSED into Vt layout (d,t).  MODE 1: fp32 out + bias.
template <int MODE>
__global__ __launch_bounds__(256) void gemm_kernel(
    const _Float16* __restrict__ A, const _Float16* __restrict__ Bfrag,
    const float* __restrict__ bias, int M, int N, int K,
    float* __restrict__ outF,
    _Float16* __restrict__ Qd, _Float16* __restrict__ Kd, _Float16* __restrict__ Vt) {
  __shared__ _Float16 As[3][4096];   // 24 KB, triple-buffered A ring
  int tid = threadIdx.x;
  int wave = tid >> 6, lane = tid & 63;
  int l15 = lane & 15, quad = lane >> 4;
  int wm = (wave & 1) * 64, wn = (wave >> 1) * 64;
  // XCD-chunked remap (R8: +4.5% measured): xcd owns contiguous m-chunk; m fast.
  int lin = blockIdx.y * gridDim.x + blockIdx.x;
  int xcd = lin & 7, idx = lin >> 3;
  int nmc = gridDim.x >> 3;
  int m0 = (xcd * nmc + (idx % nmc)) * 128;
  int n0 = (idx / nmc) * 128;
  v4f zero = {0.f, 0.f, 0.f, 0.f};
  v4f acc[4][4];
#pragma unroll
  for (int i = 0; i < 4; ++i)
#pragma unroll
    for (int j = 0; j < 4; ++j) acc[i][j] = zero;

  int ar0 = tid >> 2;          // per-block row 0..63 (chunk 1: +64)
  int akc = (tid & 3) * 8;
  const _Float16* Ap = A + (size_t)(m0 + ar0) * K + akc;
  const int ktiles = K >> 5;
  const _Float16* Bp = Bfrag + (size_t)((n0 + wn) >> 4) * ktiles * 512 + lane * 8;

  // prologue: stage tile0 -> buf0, tile1 -> buf1 (4 loads in flight)
  {
    _Float16* w0 = &As[0][0] + wave * 512;
    load_lds16(Ap,                  w0);
    load_lds16(Ap + (size_t)64 * K, w0 + 2048);
    _Float16* w1 = &As[1][0] + wave * 512;
    load_lds16(Ap + 32,                  w1);
    load_lds16(Ap + 32 + (size_t)64 * K, w1 + 2048);
  }

  int cur = 0;
  for (int kt = 0; kt < ktiles; ++kt) {
    if (kt + 1 < ktiles) {
      asm volatile("s_waitcnt vmcnt(2)" ::: "memory");   // tile kt landed (mine)
    } else {
      asm volatile("s_waitcnt vmcnt(0)" ::: "memory");
    }
    __builtin_amdgcn_s_barrier();                        // everyone's tile kt landed
    __builtin_amdgcn_sched_barrier(0);
    // B-frags first: compiler's own wait before MFMA then leaves the newest
    // (stage) loads outstanding -> ring depth preserved.
    half8 bf[4];
#pragma unroll
    for (int ni = 0; ni < 4; ++ni)
      bf[ni] = *(const half8*)(Bp + ((size_t)ni * ktiles + kt) * 512);
    __builtin_amdgcn_sched_barrier(0);
    if (kt + 2 < ktiles) {   // stage tile kt+2 into the buffer last read at kt-1
      int stg = cur == 0 ? 2 : cur - 1;                  // (cur+2) mod 3
      _Float16* nx = &As[stg][0] + wave * 512;
      load_lds16(Ap + (kt + 2) * 32,                  nx);
      load_lds16(Ap + (kt + 2) * 32 + (size_t)64 * K, nx + 2048);
    }
    __builtin_amdgcn_sched_barrier(0);
    half8 af[4];
#pragma unroll
    for (int i = 0; i < 4; ++i)
      af[i] = *(const half8*)&As[cur][(wm + i * 16 + l15) * 32 + quad * 8];
#pragma unroll
    for (int mi = 0; mi < 4; ++mi)
#pragma unroll
      for (int ni = 0; ni < 4; ++ni)
        acc[mi][ni] = __builtin_amdgcn_mfma_f32_16x16x32_f16(af[mi], bf[ni], acc[mi][ni], 0, 0, 0);
    cur = cur == 2 ? 0 : cur + 1;
  }
  // epilogue: C layout row=quad*4+r, col=l15
  float bv[4];
#pragma unroll
  for (int ni = 0; ni < 4; ++ni) bv[ni] = bias[n0 + wn + ni * 16 + l15];
#pragma unroll
  for (int mi = 0; mi < 4; ++mi) {
#pragma unroll
    for (int ni = 0; ni < 4; ++ni) {
      int n = n0 + wn + ni * 16 + l15;
      if (MODE == 1) {
#pragma unroll
        for (int r = 0; r < 4; ++r) {
          int m = m0 + wm + mi * 16 + quad * 4 + r;
          outF[(size_t)m * N + n] = acc[mi][ni][r] + bv[ni];
        }
      } else {
        int h = (n >> 6) & 15, d = n & 63;
        if (n < 2048) {   // Q (scaled) / K, (b,h,t,d) layout — wave-uniform branch
#pragma unroll
          for (int r = 0; r < 4; ++r) {
            int m = m0 + wm + mi * 16 + quad * 4 + r;
            int b = m >> 10, t = m & 1023;
            size_t idx2 = ((size_t)(b * NHEAD + h) * T_SEQ + t) * HDIM + d;
            float v = acc[mi][ni][r] + bv[ni];
            // 0.125 * log2(e): softmax runs in exp2 domain
            if (n < 1024) Qd[idx2] = (_Float16)(v * 0.18033688f);
            else          Kd[idx2] = (_Float16)v;
          }
        } else {          // V: direct transposed store, (b,h,d,t) layout
          int mb = m0 + wm + mi * 16 + quad * 4;
          int b = mb >> 10, t = mb & 1023;
          half4h vk;
#pragma unroll
          for (int r = 0; r < 4; ++r) vk[r] = (_Float16)(acc[mi][ni][r] + bv[ni]);
          *(half4h*)&Vt[((size_t)(b * NHEAD + h) * HDIM + d) * T_SEQ + t] = vk;
        }
      }
    }
  }
}

// ------- flash attention: 8 waves / 128 q-rows per block, 64-key tiles ------
// S^T = K Q^T: lane owns ONE q-row (col=l15), 16 keys in regs. O^T = V^T P^T.
// K/V in a 3-BUFFER LDS ring (stage->use distance 2 tiles). T13 defer-max:
// skip O/l rescale while per-tile max growth <= 8 (exp2 domain) -> P bounded by
// 2^8; fp16 rel-precision magnitude-independent, l/PV accumulate fp32 -> numerics
// unchanged. Heavy q-tiles dispatch first.
__global__ __launch_bounds__(512) void attn_kernel(const _Float16* __restrict__ Qg,
                                                   const _Float16* __restrict__ Kk,
                                                   const _Float16* __restrict__ Vt,
                                                   const int* __restrict__ x_lens,
                                                   _Float16* __restrict__ att) {
  __shared__ _Float16 Ks[3][2][2048];   // [buf][d-half][key*32 + chunk]
  __shared__ _Float16 Vs[3][2][2048];   // [buf][key-half][d*32 + chunk]
  __shared__ _Float16 Pb[8][16 * 72];   // per-wave roundtrip: [q_local][key or d]
  int blk = blockIdx.x;
  int qt = 7 - (blk >> 7);    // heavy-first: work/block ~ qt; dispatch big ones early
  int bh = blk & 127;
  int h  = bh & 15;
  int b  = bh >> 4;
  int t0 = qt * 128;
  int len = x_lens[b];
  int tid = threadIdx.x;
  int wave = tid >> 6, lane = tid & 63;
  int l15 = lane & 15, quad = lane >> 4;
  size_t plane = (size_t)(b * NHEAD + h) * (T_SEQ * HDIM);
  int qrow = t0 + wave * 16;
  int qabs = qrow + l15;
  const _Float16* Qp = Qg + plane + (size_t)qabs * HDIM + quad * 8;
  half8 qf0 = *(const half8*)Qp;          // B-frag: Q[q=l15][d=quad*8+j]
  half8 qf1 = *(const half8*)(Qp + 32);
  v4f zero = {0.f, 0.f, 0.f, 0.f};
  float m_i = -1e30f, l_i = 0.f;          // per-lane: one q-row
  v4f Ov[4];                              // O^T C-layout: row d=16nt+quad*4+r, col q=l15
#pragma unroll
  for (int nt = 0; nt < 4; ++nt) Ov[nt] = zero;

  int jmaxb = min(t0 + 127, len - 1);
  int ntile = (jmaxb >> 6) + 1;
  int wjmax = min(qrow + 15, len - 1);

  // staging: 16 units of 1KB; wave w handles units w*2, w*2+1
  const _Float16* src[2];
  _Float16* dst0[2];   // destination in buffer 0; buffer b: +b*4096 halves
  int strd[2];
#pragma unroll
  for (int i = 0; i < 2; ++i) {
    int u = wave * 2 + i;
    int q = u & 3, hf = (u >> 2) & 1;
    if (u < 8) {
      src[i] = Kk + plane + (size_t)(q * 16 + (lane >> 2)) * HDIM + hf * 32 + (lane & 3) * 8;
      dst0[i] = &Ks[0][hf][0] + q * 512;
      strd[i] = 64 * HDIM;
    } else {
      src[i] = Vt + plane + (size_t)(q * 16 + (lane >> 2)) * T_SEQ + hf * 32 + (lane & 3) * 8;
      dst0[i] = &Vs[0][hf][0] + q * 512;
      strd[i] = 64;
    }
  }

  // prologue: stage tile 0 -> buf 0, tile 1 -> buf 1
#pragma unroll
  for (int i = 0; i < 2; ++i) { load_lds16(src[i], dst0[i]); src[i] += strd[i]; }
  if (ntile > 1) {
#pragma unroll
    for (int i = 0; i < 2; ++i) { load_lds16(src[i], dst0[i] + 4096); src[i] += strd[i]; }
  }

  int cur = 0;
  for (int jt = 0; jt < ntile; ++jt) {
    int j0 = jt * 64;
    __builtin_amdgcn_s_barrier();          // all waves done compute of jt-1
    if (jt + 2 < ntile) {                  // stage tile jt+2 into buf[(jt+2)%3]
      int stg = cur == 0 ? 2 : cur - 1;    // (cur+2) mod 3
#pragma unroll
      for (int i = 0; i < 2; ++i) {
        load_lds16(src[i], dst0[i] + stg * 4096);
        src[i] += strd[i];
      }
      asm volatile("s_waitcnt vmcnt(4)" ::: "memory");   // my tile-jt loads landed
    } else if (jt + 1 < ntile) {
      asm volatile("s_waitcnt vmcnt(2)" ::: "memory");
    } else {
      asm volatile("s_waitcnt vmcnt(0)" ::: "memory");
    }
    __builtin_amdgcn_s_barrier();          // everyone's tile-jt loads landed
    __builtin_amdgcn_sched_barrier(0);
    if (j0 <= wjmax) {
      v4f s[4];
      __builtin_amdgcn_s_setprio(1);
#pragma unroll
      for (int nt = 0; nt < 4; ++nt) {
        s[nt] = zero;
        half8 k0 = *(const half8*)&Ks[cur][0][(nt * 16 + l15) * 32 + quad * 8];
        half8 k1 = *(const half8*)&Ks[cur][1][(nt * 16 + l15) * 32 + quad * 8];
        s[nt] = __builtin_amdgcn_mfma_f32_16x16x32_f16(k0, qf0, s[nt], 0, 0, 0);
        s[nt] = __builtin_amdgcn_mfma_f32_16x16x32_f16(k1, qf1, s[nt], 0, 0, 0);
      }
      __builtin_amdgcn_s_setprio(0);
      float mnew = m_i;
      bool full = (j0 + 63 <= qrow) && (j0 + 63 < len);
      if (full) {
#pragma unroll
        for (int nt = 0; nt < 4; ++nt)
#pragma unroll
          for (int r = 0; r < 4; ++r)
            mnew = fmaxf(mnew, s[nt][r]);
      } else {
#pragma unroll
        for (int nt = 0; nt < 4; ++nt) {
#pragma unroll
          for (int r = 0; r < 4; ++r) {
            int key = j0 + nt * 16 + quad * 4 + r;
            float v = (key <= qabs && key < len) ? s[nt][r] : -1e30f;
            s[nt][r] = v;
            mnew = fmaxf(mnew, v);
          }
        }
      }
      mnew = fmaxf(mnew, __shfl_xor(mnew, 16));
      mnew = fmaxf(mnew, __shfl_xor(mnew, 32));
      // T13 defer-max: rescale only when some lane's max grew by > 8 (exp2 dom).
      // First tile: mnew - (-1e30) > 8 -> rescale path; alpha=exp2(-huge)=0.
      if (!__all(mnew - m_i <= 8.0f)) {
        float alpha = exp2f(m_i - mnew);
        m_i = mnew;
        l_i *= alpha;
#pragma unroll
        for (int nt = 0; nt < 4; ++nt)
#pragma unroll
          for (int r = 0; r < 4; ++r) Ov[nt][r] *= alpha;
      }
      float rsum = 0.f;
#pragma unroll
      for (int nt = 0; nt < 4; ++nt)
#pragma unroll
        for (int r = 0; r < 4; ++r) {
          float p = exp2f(s[nt][r] - m_i);
          s[nt][r] = p;
          rsum += p;
        }
      rsum += __shfl_xor(rsum, 16);
      rsum += __shfl_xor(rsum, 32);
      l_i += rsum;
#pragma unroll
      for (int nt = 0; nt < 4; ++nt) {
        half4h pk;
#pragma unroll
        for (int r = 0; r < 4; ++r) pk[r] = (_Float16)s[nt][r];
        *(half4h*)&Pb[wave][l15 * 72 + nt * 16 + quad * 4] = pk;
      }
      asm volatile("s_waitcnt lgkmcnt(0)" ::: "memory");
      half8 pf0 = *(const half8*)&Pb[wave][l15 * 72 + quad * 8];
      half8 pf1 = *(const half8*)&Pb[wave][l15 * 72 + 32 + quad * 8];
      __builtin_amdgcn_s_setprio(1);
#pragma unroll
      for (int nt = 0; nt < 4; ++nt) {
        half8 v0 = *(const half8*)&Vs[cur][0][(nt * 16 + l15) * 32 + quad * 8];
        half8 v1 = *(const half8*)&Vs[cur][1][(nt * 16 + l15) * 32 + quad * 8];
        Ov[nt] = __builtin_amdgcn_mfma_f32_16x16x32_f16(v0, pf0, Ov[nt], 0, 0, 0);
        Ov[nt] = __builtin_amdgcn_mfma_f32_16x16x32_f16(v1, pf1, Ov[nt], 0, 0, 0);
      }
      __builtin_amdgcn_s_setprio(0);
    }
    cur = cur == 2 ? 0 : cur + 1;
  }
  // epilogue: O^T regs -> Pb[q_local][d] -> coalesced row-major stores
  float inv = 1.0f / l_i;
#pragma unroll
  for (int nt = 0; nt < 4; ++nt) {
    half4h ok;
#pragma unroll
    for (int r = 0; r < 4; ++r) ok[r] = (_Float16)(Ov[nt][r] * inv);
    *(half4h*)&Pb[wave][l15 * 72 + nt * 16 + quad * 4] = ok;
  }
  asm volatile("s_waitcnt lgkmcnt(0)" ::: "memory");
  int r0 = lane >> 3, c0 = (lane & 7) * 8;
  half8 o0 = *(const half8*)&Pb[wave][r0 * 72 + c0];
  half8 o1 = *(const half8*)&Pb[wave][(r0 + 8) * 72 + c0];
  *(half8*)&att[((size_t)(b * T_SEQ) + qrow + r0) * D_MODEL + h * HDIM + c0] = o0;
  *(half8*)&att[((size_t)(b * T_SEQ) + qrow + r0 + 8) * D_MODEL + h * HDIM + c0] = o1;
}

extern "C" void kernel_launch(void* const* d_in, const int* in_sizes, int n_in,
                              void* d_out, int out_size, void* d_ws, size_t ws_size,
                              hipStream_t stream) {
  const float* x        = (const float*)d_in[0];
  const int*   x_lens   = (const int*)d_in[1];
  const float* ln_gamma = (const float*)d_in[2];
  const float* ln_beta  = (const float*)d_in[3];
  const float* w_qkv    = (const float*)d_in[4];
  const float* b_qkv    = (const float*)d_in[5];
  const float* w_out    = (const float*)d_in[6];
  const float* b_out    = (const float*)d_in[7];
  float* out = (float*)d_out;

  char* w = (char*)d_ws;
  _Float16* xn    = (_Float16*)w; w += (size_t)8192 * 1024 * 2;
  _Float16* BfQKV = (_Float16*)w; w += (size_t)3072 * 1024 * 2;
  _Float16* BfOut = (_Float16*)w; w += (size_t)1024 * 1024 * 2;
  _Float16* Qd    = (_Float16*)w; w += (size_t)8192 * 1024 * 2;
  _Float16* Kd    = (_Float16*)w; w += (size_t)8192 * 1024 * 2;
  _Float16* Vt    = (_Float16*)w; w += (size_t)8192 * 1024 * 2;   // (b,h,d,t) — written directly by gemm<0>
  _Float16* att   = (_Float16*)w; w += (size_t)8192 * 1024 * 2;

  fragize_kernel<<<(3072 * 1024 / 8) / 256, 256, 0, stream>>>(w_qkv, BfQKV, 3072, 1024);
  fragize_kernel<<<(1024 * 1024 / 8) / 256, 256, 0, stream>>>(w_out, BfOut, 1024, 1024);
  ln_kernel<<<8192, 256, 0, stream>>>(x, ln_gamma, ln_beta, xn);
  gemm_kernel<0><<<dim3(8192 / 128, 3072 / 128), 256, 0, stream>>>(
      xn, BfQKV, b_qkv, 8192, 3072, 1024, nullptr, Qd, Kd, Vt);
  attn_kernel<<<1024, 512, 0, stream>>>(Qd, Kd, Vt, x_lens, att);
  gemm_kernel<1><<<dim3(8192 / 128, 1024 / 128), 256, 0, stream>>>(
      att, BfOut, b_out, 8192, 1024, 1024, out, nullptr, nullptr, nullptr);
}

// Round 14
// 228.708 us; speedup vs baseline: 1.0706x; 1.0308x over previous
//
#include <hip/hip_runtime.h>

#define D_MODEL 1024
#define T_SEQ   1024
#define BATCH   8
#define NHEAD   16
#define HDIM    64

typedef float      v4f   __attribute__((ext_vector_type(4)));
typedef _Float16   half8 __attribute__((ext_vector_type(8)));
typedef _Float16   half4h __attribute__((ext_vector_type(4)));
typedef unsigned int ui4 __attribute__((ext_vector_type(4)));

// async global->LDS, 16B per lane, dest = wave-uniform base + lane*16
__device__ __forceinline__ void load_lds16(const _Float16* g, _Float16* l) {
  __builtin_amdgcn_global_load_lds(
      (const __attribute__((address_space(1))) unsigned int*)g,
      (__attribute__((address_space(3))) unsigned int*)l, 16, 0, 0);
}

// ---- fused prologue: LN (blocks 0..8191) + fragize QKV (8192..9727) +
//      fragize out-proj (9728..10239). All independent, memory-bound; merging
//      streams ~73MB of traffic concurrently instead of 3 serial part-fills. ----
__global__ __launch_bounds__(256) void prep_kernel(
    const float* __restrict__ x, const float* __restrict__ gamma,
    const float* __restrict__ beta, _Float16* __restrict__ xn,
    const float* __restrict__ Wqkv, _Float16* __restrict__ BfQKV,
    const float* __restrict__ Wout, _Float16* __restrict__ BfOut) {
  int blk = blockIdx.x;
  int tid = threadIdx.x;
  if (blk < 8192) {
    // ---------------- LayerNorm (fp32 in) -> fp16 xn ----------------
    const float* xr = x + (size_t)blk * D_MODEL;
    v4f xv = *(const v4f*)(xr + tid * 4);
    float s  = xv[0] + xv[1] + xv[2] + xv[3];
    float sq = xv[0]*xv[0] + xv[1]*xv[1] + xv[2]*xv[2] + xv[3]*xv[3];
#pragma unroll
    for (int off = 32; off > 0; off >>= 1) {
      s  += __shfl_xor(s, off);
      sq += __shfl_xor(sq, off);
    }
    __shared__ float ps[4], psq[4];
    int wave = tid >> 6;
    if ((tid & 63) == 0) { ps[wave] = s; psq[wave] = sq; }
    __syncthreads();
    float tot  = ps[0] + ps[1] + ps[2] + ps[3];
    float totq = psq[0] + psq[1] + psq[2] + psq[3];
    float mean = tot * (1.0f / D_MODEL);
    float var  = totq * (1.0f / D_MODEL) - mean * mean;
    float rs   = rsqrtf(var + 1e-5f);
    v4f gv = *(const v4f*)(gamma + tid * 4);
    v4f bv = *(const v4f*)(beta + tid * 4);
    half4h o;
#pragma unroll
    for (int i = 0; i < 4; ++i)
      o[i] = (_Float16)((xv[i] - mean) * rs * gv[i] + bv[i]);
    *(half4h*)(xn + (size_t)blk * D_MODEL + tid * 4) = o;
  } else {
    // ---- fragize: W (K x N fp32) -> Bfrag[nt][kt][lane][8] fp16 ----
    const float* W;
    _Float16* Bf;
    int N, fblk;
    if (blk < 8192 + 1536) { W = Wqkv; Bf = BfQKV; N = 3072; fblk = blk - 8192; }
    else                   { W = Wout; Bf = BfOut; N = 1024; fblk = blk - 9728; }
    int g = fblk * 256 + tid;
    int lane = g & 63, tile = g >> 6;
    const int ktiles = 32;   // K = 1024
    int kt = tile % ktiles, nt = tile / ktiles;
    int n  = nt * 16 + (lane & 15);
    int k0 = kt * 32 + (lane >> 4) * 8;
    half8 o;
#pragma unroll
    for (int j = 0; j < 8; ++j) o[j] = (_Float16)W[(size_t)(k0 + j) * N + n];
    *(half8*)(Bf + (size_t)g * 8) = o;
  }
}

// -- 128x128 MFMA GEMM: A in 3-buffer LDS ring (counted vmcnt), B-frags from L2,
//    XCD-chunked block remap. MODE 0 epilogue: Q*(0.125*log2e), K planes (t,d);
//    V written DIRECTLY TRANSPOSED into Vt layout (d,t).  MODE 1: fp32 out + bias.
template <int MODE>
__global__ __launch_bounds__(256) void gemm_kernel(
    const _Float16* __restrict__ A, const _Float16* __restrict__ Bfrag,
    const float* __restrict__ bias, int M, int N, int K,
    float* __restrict__ outF,
    _Float16* __restrict__ Qd, _Float16* __restrict__ Kd, _Float16* __restrict__ Vt) {
  __shared__ _Float16 As[3][4096];   // 24 KB, triple-buffered A ring
  int tid = threadIdx.x;
  int wave = tid >> 6, lane = tid & 63;
  int l15 = lane & 15, quad = lane >> 4;
  int wm = (wave & 1) * 64, wn = (wave >> 1) * 64;
  // XCD-chunked remap (R8: +4.5% measured): xcd owns contiguous m-chunk; m fast.
  int lin = blockIdx.y * gridDim.x + blockIdx.x;
  int xcd = lin & 7, idx = lin >> 3;
  int nmc = gridDim.x >> 3;
  int m0 = (xcd * nmc + (idx % nmc)) * 128;
  int n0 = (idx / nmc) * 128;
  v4f zero = {0.f, 0.f, 0.f, 0.f};
  v4f acc[4][4];
#pragma unroll
  for (int i = 0; i < 4; ++i)
#pragma unroll
    for (int j = 0; j < 4; ++j) acc[i][j] = zero;

  int ar0 = tid >> 2;          // per-block row 0..63 (chunk 1: +64)
  int akc = (tid & 3) * 8;
  const _Float16* Ap = A + (size_t)(m0 + ar0) * K + akc;
  const int ktiles = K >> 5;
  const _Float16* Bp = Bfrag + (size_t)((n0 + wn) >> 4) * ktiles * 512 + lane * 8;

  // prologue: stage tile0 -> buf0, tile1 -> buf1 (4 loads in flight)
  {
    _Float16* w0 = &As[0][0] + wave * 512;
    load_lds16(Ap,                  w0);
    load_lds16(Ap + (size_t)64 * K, w0 + 2048);
    _Float16* w1 = &As[1][0] + wave * 512;
    load_lds16(Ap + 32,                  w1);
    load_lds16(Ap + 32 + (size_t)64 * K, w1 + 2048);
  }

  int cur = 0;
  for (int kt = 0; kt < ktiles; ++kt) {
    if (kt + 1 < ktiles) {
      asm volatile("s_waitcnt vmcnt(2)" ::: "memory");   // tile kt landed (mine)
    } else {
      asm volatile("s_waitcnt vmcnt(0)" ::: "memory");
    }
    __builtin_amdgcn_s_barrier();                        // everyone's tile kt landed
    __builtin_amdgcn_sched_barrier(0);
    // B-frags first: compiler's own wait before MFMA then leaves the newest
    // (stage) loads outstanding -> ring depth preserved.
    half8 bf[4];
#pragma unroll
    for (int ni = 0; ni < 4; ++ni)
      bf[ni] = *(const half8*)(Bp + ((size_t)ni * ktiles + kt) * 512);
    __builtin_amdgcn_sched_barrier(0);
    if (kt + 2 < ktiles) {   // stage tile kt+2 into the buffer last read at kt-1
      int stg = cur == 0 ? 2 : cur - 1;                  // (cur+2) mod 3
      _Float16* nx = &As[stg][0] + wave * 512;
      load_lds16(Ap + (kt + 2) * 32,                  nx);
      load_lds16(Ap + (kt + 2) * 32 + (size_t)64 * K, nx + 2048);
    }
    __builtin_amdgcn_sched_barrier(0);
    half8 af[4];
#pragma unroll
    for (int i = 0; i < 4; ++i)
      af[i] = *(const half8*)&As[cur][(wm + i * 16 + l15) * 32 + quad * 8];
#pragma unroll
    for (int mi = 0; mi < 4; ++mi)
#pragma unroll
      for (int ni = 0; ni < 4; ++ni)
        acc[mi][ni] = __builtin_amdgcn_mfma_f32_16x16x32_f16(af[mi], bf[ni], acc[mi][ni], 0, 0, 0);
    cur = cur == 2 ? 0 : cur + 1;
  }
  // epilogue: C layout row=quad*4+r, col=l15
  float bv[4];
#pragma unroll
  for (int ni = 0; ni < 4; ++ni) bv[ni] = bias[n0 + wn + ni * 16 + l15];
#pragma unroll
  for (int mi = 0; mi < 4; ++mi) {
#pragma unroll
    for (int ni = 0; ni < 4; ++ni) {
      int n = n0 + wn + ni * 16 + l15;
      if (MODE == 1) {
#pragma unroll
        for (int r = 0; r < 4; ++r) {
          int m = m0 + wm + mi * 16 + quad * 4 + r;
          outF[(size_t)m * N + n] = acc[mi][ni][r] + bv[ni];
        }
      } else {
        int h = (n >> 6) & 15, d = n & 63;
        if (n < 2048) {   // Q (scaled) / K, (b,h,t,d) layout — wave-uniform branch
#pragma unroll
          for (int r = 0; r < 4; ++r) {
            int m = m0 + wm + mi * 16 + quad * 4 + r;
            int b = m >> 10, t = m & 1023;
            size_t idx2 = ((size_t)(b * NHEAD + h) * T_SEQ + t) * HDIM + d;
            float v = acc[mi][ni][r] + bv[ni];
            // 0.125 * log2(e): softmax runs in exp2 domain
            if (n < 1024) Qd[idx2] = (_Float16)(v * 0.18033688f);
            else          Kd[idx2] = (_Float16)v;
          }
        } else {          // V: direct transposed store, (b,h,d,t) layout
          int mb = m0 + wm + mi * 16 + quad * 4;
          int b = mb >> 10, t = mb & 1023;
          half4h vk;
#pragma unroll
          for (int r = 0; r < 4; ++r) vk[r] = (_Float16)(acc[mi][ni][r] + bv[ni]);
          *(half4h*)&Vt[((size_t)(b * NHEAD + h) * HDIM + d) * T_SEQ + t] = vk;
        }
      }
    }
  }
}

// ------- flash attention: 8 waves / 128 q-rows per block, 64-key tiles ------
// S^T = K Q^T: lane owns ONE q-row (col=l15), 16 keys in regs. O^T = V^T P^T.
// K/V in a 3-BUFFER LDS ring (stage->use distance 2 tiles). T13 defer-max.
// Heavy q-tiles dispatch first.
__global__ __launch_bounds__(512) void attn_kernel(const _Float16* __restrict__ Qg,
                                                   const _Float16* __restrict__ Kk,
                                                   const _Float16* __restrict__ Vt,
                                                   const int* __restrict__ x_lens,
                                                   _Float16* __restrict__ att) {
  __shared__ _Float16 Ks[3][2][2048];   // [buf][d-half][key*32 + chunk]
  __shared__ _Float16 Vs[3][2][2048];   // [buf][key-half][d*32 + chunk]
  __shared__ _Float16 Pb[8][16 * 72];   // per-wave roundtrip: [q_local][key or d]
  int blk = blockIdx.x;
  int qt = 7 - (blk >> 7);    // heavy-first: work/block ~ qt; dispatch big ones early
  int bh = blk & 127;
  int h  = bh & 15;
  int b  = bh >> 4;
  int t0 = qt * 128;
  int len = x_lens[b];
  int tid = threadIdx.x;
  int wave = tid >> 6, lane = tid & 63;
  int l15 = lane & 15, quad = lane >> 4;
  size_t plane = (size_t)(b * NHEAD + h) * (T_SEQ * HDIM);
  int qrow = t0 + wave * 16;
  int qabs = qrow + l15;
  const _Float16* Qp = Qg + plane + (size_t)qabs * HDIM + quad * 8;
  half8 qf0 = *(const half8*)Qp;          // B-frag: Q[q=l15][d=quad*8+j]
  half8 qf1 = *(const half8*)(Qp + 32);
  v4f zero = {0.f, 0.f, 0.f, 0.f};
  float m_i = -1e30f, l_i = 0.f;          // per-lane: one q-row
  v4f Ov[4];                              // O^T C-layout: row d=16nt+quad*4+r, col q=l15
#pragma unroll
  for (int nt = 0; nt < 4; ++nt) Ov[nt] = zero;

  int jmaxb = min(t0 + 127, len - 1);
  int ntile = (jmaxb >> 6) + 1;
  int wjmax = min(qrow + 15, len - 1);

  // staging: 16 units of 1KB; wave w handles units w*2, w*2+1
  const _Float16* src[2];
  _Float16* dst0[2];   // destination in buffer 0; buffer b: +b*4096 halves
  int strd[2];
#pragma unroll
  for (int i = 0; i < 2; ++i) {
    int u = wave * 2 + i;
    int q = u & 3, hf = (u >> 2) & 1;
    if (u < 8) {
      src[i] = Kk + plane + (size_t)(q * 16 + (lane >> 2)) * HDIM + hf * 32 + (lane & 3) * 8;
      dst0[i] = &Ks[0][hf][0] + q * 512;
      strd[i] = 64 * HDIM;
    } else {
      src[i] = Vt + plane + (size_t)(q * 16 + (lane >> 2)) * T_SEQ + hf * 32 + (lane & 3) * 8;
      dst0[i] = &Vs[0][hf][0] + q * 512;
      strd[i] = 64;
    }
  }

  // prologue: stage tile 0 -> buf 0, tile 1 -> buf 1
#pragma unroll
  for (int i = 0; i < 2; ++i) { load_lds16(src[i], dst0[i]); src[i] += strd[i]; }
  if (ntile > 1) {
#pragma unroll
    for (int i = 0; i < 2; ++i) { load_lds16(src[i], dst0[i] + 4096); src[i] += strd[i]; }
  }

  int cur = 0;
  for (int jt = 0; jt < ntile; ++jt) {
    int j0 = jt * 64;
    __builtin_amdgcn_s_barrier();          // all waves done compute of jt-1
    if (jt + 2 < ntile) {                  // stage tile jt+2 into buf[(jt+2)%3]
      int stg = cur == 0 ? 2 : cur - 1;    // (cur+2) mod 3
#pragma unroll
      for (int i = 0; i < 2; ++i) {
        load_lds16(src[i], dst0[i] + stg * 4096);
        src[i] += strd[i];
      }
      asm volatile("s_waitcnt vmcnt(4)" ::: "memory");   // my tile-jt loads landed
    } else if (jt + 1 < ntile) {
      asm volatile("s_waitcnt vmcnt(2)" ::: "memory");
    } else {
      asm volatile("s_waitcnt vmcnt(0)" ::: "memory");
    }
    __builtin_amdgcn_s_barrier();          // everyone's tile-jt loads landed
    __builtin_amdgcn_sched_barrier(0);
    if (j0 <= wjmax) {
      v4f s[4];
      __builtin_amdgcn_s_setprio(1);
#pragma unroll
      for (int nt = 0; nt < 4; ++nt) {
        s[nt] = zero;
        half8 k0 = *(const half8*)&Ks[cur][0][(nt * 16 + l15) * 32 + quad * 8];
        half8 k1 = *(const half8*)&Ks[cur][1][(nt * 16 + l15) * 32 + quad * 8];
        s[nt] = __builtin_amdgcn_mfma_f32_16x16x32_f16(k0, qf0, s[nt], 0, 0, 0);
        s[nt] = __builtin_amdgcn_mfma_f32_16x16x32_f16(k1, qf1, s[nt], 0, 0, 0);
      }
      __builtin_amdgcn_s_setprio(0);
      float mnew = m_i;
      bool full = (j0 + 63 <= qrow) && (j0 + 63 < len);
      if (full) {
#pragma unroll
        for (int nt = 0; nt < 4; ++nt)
#pragma unroll
          for (int r = 0; r < 4; ++r)
            mnew = fmaxf(mnew, s[nt][r]);
      } else {
#pragma unroll
        for (int nt = 0; nt < 4; ++nt) {
#pragma unroll
          for (int r = 0; r < 4; ++r) {
            int key = j0 + nt * 16 + quad * 4 + r;
            float v = (key <= qabs && key < len) ? s[nt][r] : -1e30f;
            s[nt][r] = v;
            mnew = fmaxf(mnew, v);
          }
        }
      }
      mnew = fmaxf(mnew, __shfl_xor(mnew, 16));
      mnew = fmaxf(mnew, __shfl_xor(mnew, 32));
      // T13 defer-max: rescale only when some lane's max grew by > 8 (exp2 dom).
      if (!__all(mnew - m_i <= 8.0f)) {
        float alpha = exp2f(m_i - mnew);
        m_i = mnew;
        l_i *= alpha;
#pragma unroll
        for (int nt = 0; nt < 4; ++nt)
#pragma unroll
          for (int r = 0; r < 4; ++r) Ov[nt][r] *= alpha;
      }
      float rsum = 0.f;
#pragma unroll
      for (int nt = 0; nt < 4; ++nt)
#pragma unroll
        for (int r = 0; r < 4; ++r) {
          float p = exp2f(s[nt][r] - m_i);
          s[nt][r] = p;
          rsum += p;
        }
      rsum += __shfl_xor(rsum, 16);
      rsum += __shfl_xor(rsum, 32);
      l_i += rsum;
#pragma unroll
      for (int nt = 0; nt < 4; ++nt) {
        half4h pk;
#pragma unroll
        for (int r = 0; r < 4; ++r) pk[r] = (_Float16)s[nt][r];
        *(half4h*)&Pb[wave][l15 * 72 + nt * 16 + quad * 4] = pk;
      }
      asm volatile("s_waitcnt lgkmcnt(0)" ::: "memory");
      half8 pf0 = *(const half8*)&Pb[wave][l15 * 72 + quad * 8];
      half8 pf1 = *(const half8*)&Pb[wave][l15 * 72 + 32 + quad * 8];
      __builtin_amdgcn_s_setprio(1);
#pragma unroll
      for (int nt = 0; nt < 4; ++nt) {
        half8 v0 = *(const half8*)&Vs[cur][0][(nt * 16 + l15) * 32 + quad * 8];
        half8 v1 = *(const half8*)&Vs[cur][1][(nt * 16 + l15) * 32 + quad * 8];
        Ov[nt] = __builtin_amdgcn_mfma_f32_16x16x32_f16(v0, pf0, Ov[nt], 0, 0, 0);
        Ov[nt] = __builtin_amdgcn_mfma_f32_16x16x32_f16(v1, pf1, Ov[nt], 0, 0, 0);
      }
      __builtin_amdgcn_s_setprio(0);
    }
    cur = cur == 2 ? 0 : cur + 1;
  }
  // epilogue: O^T regs -> Pb[q_local][d] -> coalesced row-major stores
  float inv = 1.0f / l_i;
#pragma unroll
  for (int nt = 0; nt < 4; ++nt) {
    half4h ok;
#pragma unroll
    for (int r = 0; r < 4; ++r) ok[r] = (_Float16)(Ov[nt][r] * inv);
    *(half4h*)&Pb[wave][l15 * 72 + nt * 16 + quad * 4] = ok;
  }
  asm volatile("s_waitcnt lgkmcnt(0)" ::: "memory");
  int r0 = lane >> 3, c0 = (lane & 7) * 8;
  half8 o0 = *(const half8*)&Pb[wave][r0 * 72 + c0];
  half8 o1 = *(const half8*)&Pb[wave][(r0 + 8) * 72 + c0];
  *(half8*)&att[((size_t)(b * T_SEQ) + qrow + r0) * D_MODEL + h * HDIM + c0] = o0;
  *(half8*)&att[((size_t)(b * T_SEQ) + qrow + r0 + 8) * D_MODEL + h * HDIM + c0] = o1;
}

extern "C" void kernel_launch(void* const* d_in, const int* in_sizes, int n_in,
                              void* d_out, int out_size, void* d_ws, size_t ws_size,
                              hipStream_t stream) {
  const float* x        = (const float*)d_in[0];
  const int*   x_lens   = (const int*)d_in[1];
  const float* ln_gamma = (const float*)d_in[2];
  const float* ln_beta  = (const float*)d_in[3];
  const float* w_qkv    = (const float*)d_in[4];
  const float* b_qkv    = (const float*)d_in[5];
  const float* w_out    = (const float*)d_in[6];
  const float* b_out    = (const float*)d_in[7];
  float* out = (float*)d_out;

  char* w = (char*)d_ws;
  _Float16* xn    = (_Float16*)w; w += (size_t)8192 * 1024 * 2;
  _Float16* BfQKV = (_Float16*)w; w += (size_t)3072 * 1024 * 2;
  _Float16* BfOut = (_Float16*)w; w += (size_t)1024 * 1024 * 2;
  _Float16* Qd    = (_Float16*)w; w += (size_t)8192 * 1024 * 2;
  _Float16* Kd    = (_Float16*)w; w += (size_t)8192 * 1024 * 2;
  _Float16* Vt    = (_Float16*)w; w += (size_t)8192 * 1024 * 2;   // (b,h,d,t) — written directly by gemm<0>
  _Float16* att   = (_Float16*)w; w += (size_t)8192 * 1024 * 2;

  prep_kernel<<<10240, 256, 0, stream>>>(x, ln_gamma, ln_beta, xn,
                                         w_qkv, BfQKV, w_out, BfOut);
  gemm_kernel<0><<<dim3(8192 / 128, 3072 / 128), 256, 0, stream>>>(
      xn, BfQKV, b_qkv, 8192, 3072, 1024, nullptr, Qd, Kd, Vt);
  attn_kernel<<<1024, 512, 0, stream>>>(Qd, Kd, Vt, x_lens, att);
  gemm_kernel<1><<<dim3(8192 / 128, 1024 / 128), 256, 0, stream>>>(
      att, BfOut, b_out, 8192, 1024, 1024, out, nullptr, nullptr, nullptr);
}